// Round 11
// baseline (690.930 us; speedup 1.0000x reference)
//
#include <hip/hip_runtime.h>
#include <cstdint>
#include <cstddef>

// ---------------------------------------------------------------------------
// RGCN 3-layer + FC head. 128x128/4-wave bf16 MFMA GEMM (proven structure,
// operand-swapped MFMA -> 4-consecutive-col epilogue with 8B/16B stores) +
// CSR gather aggregation (flattened per-node edge loop, 16B/lane loads).
// ws peak = 253,845,504 B (proven).
// ---------------------------------------------------------------------------

typedef short bf16x8 __attribute__((ext_vector_type(8)));
typedef float f32x4 __attribute__((ext_vector_type(4)));

#define GF_BIAS 1
#define GF_RELU 2
#define GF_BF16 4

__device__ __forceinline__ unsigned short f2bf(float f) {
    unsigned u = __float_as_uint(f);
    return (unsigned short)((u + 0x7FFFu + ((u >> 16) & 1u)) >> 16);
}
__device__ __forceinline__ float bf2f(unsigned short h) {
    return __uint_as_float((unsigned)h << 16);
}

__global__ __launch_bounds__(256) void zero_kernel(float* __restrict__ p, long n4)
{
    long i = (long)blockIdx.x * 256 + threadIdx.x;
    if (i < n4) ((float4*)p)[i] = make_float4(0.f, 0.f, 0.f, 0.f);
}

__global__ __launch_bounds__(256) void count_kernel(
    const int* __restrict__ dst, const int* __restrict__ et,
    int* __restrict__ cnt, int E)
{
    int e = blockIdx.x * 256 + threadIdx.x;
    if (e < E) atomicAdd(&cnt[dst[e] * 3 + et[e]], 1);
}

// ---- 2-level exclusive scan over S ints ----
__global__ __launch_bounds__(256) void scanA(
    const int* __restrict__ cnt, int* __restrict__ base,
    int* __restrict__ bsum, int S)
{
    __shared__ int sh[256];
    int i = blockIdx.x * 256 + threadIdx.x;
    int v = (i < S) ? cnt[i] : 0;
    sh[threadIdx.x] = v;
    __syncthreads();
#pragma unroll
    for (int off = 1; off < 256; off <<= 1) {
        int t = (threadIdx.x >= off) ? sh[threadIdx.x - off] : 0;
        __syncthreads();
        sh[threadIdx.x] += t;
        __syncthreads();
    }
    if (i < S) base[i] = sh[threadIdx.x] - v;
    if (threadIdx.x == 255) bsum[blockIdx.x] = sh[255];
}

__global__ __launch_bounds__(512) void scanB(int* __restrict__ bsum, int NB)
{
    __shared__ int sh[512];
    int t = threadIdx.x;
    int v = (t < NB) ? bsum[t] : 0;
    sh[t] = v;
    __syncthreads();
#pragma unroll
    for (int off = 1; off < 512; off <<= 1) {
        int u = (t >= off) ? sh[t - off] : 0;
        __syncthreads();
        sh[t] += u;
        __syncthreads();
    }
    if (t < NB) bsum[t] = sh[t] - v;
}

__global__ __launch_bounds__(256) void scanC(
    int* __restrict__ base, const int* __restrict__ bsum, int S)
{
    int i = blockIdx.x * 256 + threadIdx.x;
    if (i < S) base[i] += bsum[blockIdx.x];
}

// fill: decrements cnt back to zero; writes base[S] = E sentinel.
__global__ __launch_bounds__(256) void fill_kernel(
    const int* __restrict__ src, const int* __restrict__ dst,
    const int* __restrict__ et, int* __restrict__ base,
    int* __restrict__ cnt, int* __restrict__ elist, int E, int S)
{
    int e = blockIdx.x * 256 + threadIdx.x;
    if (e == 0) base[S] = E;
    if (e >= E) return;
    int seg = dst[e] * 3 + et[e];
    int old = atomicSub(&cnt[seg], 1);
    elist[base[seg] + old - 1] = src[e];
}

// ---- tiled coalesced transposes (f32 -> bf16, out[j][k] = src[k][j]) ----
__global__ __launch_bounds__(256) void tr1_tiled(
    const float* __restrict__ W1, const float* __restrict__ root1,
    unsigned short* __restrict__ W1t)
{
    __shared__ float sh[32][33];
    int bk = blockIdx.x & 31, bj = blockIdx.x >> 5;
    int tc = threadIdx.x & 31, tr = threadIdx.x >> 5;
    int k0 = bk * 32, j0 = bj * 32;
#pragma unroll
    for (int i = 0; i < 4; ++i) {
        int k = k0 + tr + i * 8;
        float v = (k < 768) ? W1[(size_t)k * 1024 + j0 + tc]
                            : root1[(size_t)(k - 768) * 1024 + j0 + tc];
        sh[tr + i * 8][tc] = v;
    }
    __syncthreads();
#pragma unroll
    for (int i = 0; i < 4; ++i)
        W1t[(size_t)(j0 + tr + i * 8) * 1024 + k0 + tc] = f2bf(sh[tc][tr + i * 8]);
}

__global__ __launch_bounds__(256) void tr2_tiled(
    const float* __restrict__ root2, const float* __restrict__ W2,
    unsigned short* __restrict__ W2cat)
{
    __shared__ float sh[32][33];
    int bk = blockIdx.x & 31, br = blockIdx.x >> 5;
    int tc = threadIdx.x & 31, tr = threadIdx.x >> 5;
    int k0 = bk * 32, r0 = br * 32;
    int s = r0 >> 9, j0 = r0 & 511;
    const float* src = (s == 0) ? root2 : W2 + (size_t)(s - 1) * 524288;
#pragma unroll
    for (int i = 0; i < 4; ++i)
        sh[tr + i * 8][tc] = src[(size_t)(k0 + tr + i * 8) * 512 + j0 + tc];
    __syncthreads();
#pragma unroll
    for (int i = 0; i < 4; ++i)
        W2cat[(size_t)(r0 + tr + i * 8) * 1024 + k0 + tc] = f2bf(sh[tc][tr + i * 8]);
}

__global__ __launch_bounds__(256) void tr3_tiled(
    const float* __restrict__ root3, const float* __restrict__ W3,
    unsigned short* __restrict__ W3cat)
{
    __shared__ float sh[32][33];
    int bk = blockIdx.x & 15, br = blockIdx.x >> 4;
    int tc = threadIdx.x & 31, tr = threadIdx.x >> 5;
    int k0 = bk * 32, r0 = br * 32;
    int s = r0 >> 7, j0 = r0 & 127;
    const float* src = (s == 0) ? root3 : W3 + (size_t)(s - 1) * 65536;
#pragma unroll
    for (int i = 0; i < 4; ++i)
        sh[tr + i * 8][tc] = src[(size_t)(k0 + tr + i * 8) * 128 + j0 + tc];
    __syncthreads();
#pragma unroll
    for (int i = 0; i < 4; ++i)
        W3cat[(size_t)(r0 + tr + i * 8) * 512 + k0 + tc] = f2bf(sh[tc][tr + i * 8]);
}

__global__ __launch_bounds__(256) void bias_cat(
    float* __restrict__ b2cat, float* __restrict__ b3cat,
    const float* __restrict__ b2, const float* __restrict__ b3)
{
    int i = blockIdx.x * 256 + threadIdx.x;
    if (i < 2048) b2cat[i] = (i < 512) ? b2[i] : 0.f;
    else if (i < 2560) { int j = i - 2048; b3cat[j] = (j < 128) ? b3[j] : 0.f; }
}

__global__ __launch_bounds__(256) void conv_bf16(
    const float* __restrict__ s, unsigned short* __restrict__ d, long n8)
{
    long i = (long)blockIdx.x * 256 + threadIdx.x;
    if (i >= n8) return;
    const float* p = s + i * 8;
    float4 a = *(const float4*)p, b = *(const float4*)(p + 4);
    ushort4 o0, o1;
    o0.x = f2bf(a.x); o0.y = f2bf(a.y); o0.z = f2bf(a.z); o0.w = f2bf(a.w);
    o1.x = f2bf(b.x); o1.y = f2bf(b.y); o1.z = f2bf(b.z); o1.w = f2bf(b.w);
    *(ushort4*)(d + i * 8) = o0;
    *(ushort4*)(d + i * 8 + 4) = o1;
}

// Layer-1 aggregate: block = 4 waves, node n. Waves 0-2: relation w via two
// 32-lane groups (2 edges in flight, 16B/lane), fold with shfl_xor(32).
__global__ __launch_bounds__(256) void agg1_kernel(
    const unsigned short* __restrict__ xb, const int* __restrict__ base,
    const int* __restrict__ elist, unsigned short* __restrict__ Xcat)
{
    int n = blockIdx.x;
    int w = threadIdx.x >> 6, l = threadIdx.x & 63;
    if (w == 3) {
        *(ushort4*)&Xcat[(size_t)n * 1024 + 768 + l * 4] =
            *(const ushort4*)&xb[(size_t)n * 256 + l * 4];
        return;
    }
    int seg = n * 3 + w;
    int st = base[seg], len = base[seg + 1] - st;
    float norm = 1.0f / (float)(len > 0 ? len : 1);
    int g = l >> 5, c8 = (l & 31) * 8;
    float a[8];
#pragma unroll
    for (int j = 0; j < 8; ++j) a[j] = 0.f;
    for (int i = g; i < len; i += 2) {
        const unsigned short* q = xb + (size_t)elist[st + i] * 256 + c8;
        ushort4 v0 = *(const ushort4*)q;
        ushort4 v1 = *(const ushort4*)(q + 4);
        a[0] += bf2f(v0.x); a[1] += bf2f(v0.y); a[2] += bf2f(v0.z); a[3] += bf2f(v0.w);
        a[4] += bf2f(v1.x); a[5] += bf2f(v1.y); a[6] += bf2f(v1.z); a[7] += bf2f(v1.w);
    }
#pragma unroll
    for (int j = 0; j < 8; ++j) a[j] += __shfl_xor(a[j], 32);
    if (l < 32) {
        ushort4 o0, o1;
        o0.x = f2bf(a[0] * norm); o0.y = f2bf(a[1] * norm);
        o0.z = f2bf(a[2] * norm); o0.w = f2bf(a[3] * norm);
        o1.x = f2bf(a[4] * norm); o1.y = f2bf(a[5] * norm);
        o1.z = f2bf(a[6] * norm); o1.w = f2bf(a[7] * norm);
        unsigned short* d = Xcat + (size_t)n * 1024 + w * 256 + c8;
        *(ushort4*)d = o0;
        *(ushort4*)(d + 4) = o1;
    }
}

// Fused layer-2 aggregate over H2all [NP][2048] (root | r0 | r1 | r2).
// Block = 4 waves = 4 nodes; lane owns 8 cols (16B). FLATTENED: one loop over
// the node's contiguous edge range (segments adjacent in elist), relation and
// norm selected per edge by two compares; 2-deep ILP unroll.
__global__ __launch_bounds__(256) void agg2_fused(
    const unsigned short* __restrict__ H2all, unsigned short* __restrict__ h2b,
    const int* __restrict__ base, const int* __restrict__ elist)
{
    int w = threadIdx.x >> 6, l = threadIdx.x & 63;
    int n = blockIdx.x * 4 + w;
    int c8 = l * 8;
    const unsigned short* rowN = H2all + (size_t)n * 2048 + c8;
    float a[8];
    {
        ushort4 r0 = *(const ushort4*)rowN;
        ushort4 r1 = *(const ushort4*)(rowN + 4);
        a[0] = bf2f(r0.x); a[1] = bf2f(r0.y); a[2] = bf2f(r0.z); a[3] = bf2f(r0.w);
        a[4] = bf2f(r1.x); a[5] = bf2f(r1.y); a[6] = bf2f(r1.z); a[7] = bf2f(r1.w);
    }
    int s0 = base[n * 3], s1b = base[n * 3 + 1];
    int s2b = base[n * 3 + 2], s3 = base[n * 3 + 3];
    int l0 = s1b - s0, l1 = s2b - s1b, l2 = s3 - s2b;
    float nm0 = 1.f / (float)(l0 > 0 ? l0 : 1);
    float nm1 = 1.f / (float)(l1 > 0 ? l1 : 1);
    float nm2 = 1.f / (float)(l2 > 0 ? l2 : 1);
    int i = s0;
    for (; i + 2 <= s3; i += 2) {
        int ia = i, ib = i + 1;
        int ra = (ia >= s1b) + (ia >= s2b);
        int rb = (ib >= s1b) + (ib >= s2b);
        float wa = (ia < s1b) ? nm0 : ((ia < s2b) ? nm1 : nm2);
        float wb = (ib < s1b) ? nm0 : ((ib < s2b) ? nm1 : nm2);
        const unsigned short* qa =
            H2all + (size_t)elist[ia] * 2048 + 512 * (1 + ra) + c8;
        const unsigned short* qb =
            H2all + (size_t)elist[ib] * 2048 + 512 * (1 + rb) + c8;
        ushort4 u0 = *(const ushort4*)qa, u1 = *(const ushort4*)(qa + 4);
        ushort4 v0 = *(const ushort4*)qb, v1 = *(const ushort4*)(qb + 4);
        a[0] += bf2f(u0.x) * wa + bf2f(v0.x) * wb;
        a[1] += bf2f(u0.y) * wa + bf2f(v0.y) * wb;
        a[2] += bf2f(u0.z) * wa + bf2f(v0.z) * wb;
        a[3] += bf2f(u0.w) * wa + bf2f(v0.w) * wb;
        a[4] += bf2f(u1.x) * wa + bf2f(v1.x) * wb;
        a[5] += bf2f(u1.y) * wa + bf2f(v1.y) * wb;
        a[6] += bf2f(u1.z) * wa + bf2f(v1.z) * wb;
        a[7] += bf2f(u1.w) * wa + bf2f(v1.w) * wb;
    }
    if (i < s3) {
        int r = (i >= s1b) + (i >= s2b);
        float wN = (i < s1b) ? nm0 : ((i < s2b) ? nm1 : nm2);
        const unsigned short* q =
            H2all + (size_t)elist[i] * 2048 + 512 * (1 + r) + c8;
        ushort4 u0 = *(const ushort4*)q, u1 = *(const ushort4*)(q + 4);
        a[0] += bf2f(u0.x) * wN; a[1] += bf2f(u0.y) * wN;
        a[2] += bf2f(u0.z) * wN; a[3] += bf2f(u0.w) * wN;
        a[4] += bf2f(u1.x) * wN; a[5] += bf2f(u1.y) * wN;
        a[6] += bf2f(u1.z) * wN; a[7] += bf2f(u1.w) * wN;
    }
    ushort4 o0, o1;
    o0.x = f2bf(fmaxf(a[0], 0.f)); o0.y = f2bf(fmaxf(a[1], 0.f));
    o0.z = f2bf(fmaxf(a[2], 0.f)); o0.w = f2bf(fmaxf(a[3], 0.f));
    o1.x = f2bf(fmaxf(a[4], 0.f)); o1.y = f2bf(fmaxf(a[5], 0.f));
    o1.z = f2bf(fmaxf(a[6], 0.f)); o1.w = f2bf(fmaxf(a[7], 0.f));
    unsigned short* d = h2b + (size_t)n * 512 + c8;
    *(ushort4*)d = o0;
    *(ushort4*)(d + 4) = o1;
}

// Fused layer-3 aggregate + FC head. Block = 4 waves = 4 nodes. FLATTENED
// edge loop over 4 lane-groups of 16 (16B/lane), fold shfl_xor(16,32).
__global__ __launch_bounds__(256) void agg3_head(
    const unsigned short* __restrict__ H3cat, const float* __restrict__ fcw,
    const float* __restrict__ fcb, const int* __restrict__ base,
    const int* __restrict__ elist, float* __restrict__ out)
{
    __shared__ float sh[4][128];
    int wid = threadIdx.x >> 6, lane = threadIdx.x & 63;
    int n = blockIdx.x * 4 + wid;
    int g = lane >> 4, c8 = (lane & 15) * 8;
    int s0 = base[n * 3], s1b = base[n * 3 + 1];
    int s2b = base[n * 3 + 2], s3 = base[n * 3 + 3];
    int l0 = s1b - s0, l1 = s2b - s1b, l2 = s3 - s2b;
    float nm0 = 1.f / (float)(l0 > 0 ? l0 : 1);
    float nm1 = 1.f / (float)(l1 > 0 ? l1 : 1);
    float nm2 = 1.f / (float)(l2 > 0 ? l2 : 1);
    float a[8];
#pragma unroll
    for (int j = 0; j < 8; ++j) a[j] = 0.f;
    for (int i = s0 + g; i < s3; i += 4) {
        int r = (i >= s1b) + (i >= s2b);
        float wN = (i < s1b) ? nm0 : ((i < s2b) ? nm1 : nm2);
        const unsigned short* q =
            H3cat + (size_t)elist[i] * 512 + 128 * (1 + r) + c8;
        ushort4 u0 = *(const ushort4*)q, u1 = *(const ushort4*)(q + 4);
        a[0] += bf2f(u0.x) * wN; a[1] += bf2f(u0.y) * wN;
        a[2] += bf2f(u0.z) * wN; a[3] += bf2f(u0.w) * wN;
        a[4] += bf2f(u1.x) * wN; a[5] += bf2f(u1.y) * wN;
        a[6] += bf2f(u1.z) * wN; a[7] += bf2f(u1.w) * wN;
    }
#pragma unroll
    for (int j = 0; j < 8; ++j) {
        a[j] += __shfl_xor(a[j], 16);
        a[j] += __shfl_xor(a[j], 32);
    }
    if (lane < 16) {
        const unsigned short* rt = H3cat + (size_t)n * 512 + c8;
        ushort4 r0 = *(const ushort4*)rt, r1 = *(const ushort4*)(rt + 4);
        sh[wid][c8 + 0] = fmaxf(a[0] + bf2f(r0.x), 0.f);
        sh[wid][c8 + 1] = fmaxf(a[1] + bf2f(r0.y), 0.f);
        sh[wid][c8 + 2] = fmaxf(a[2] + bf2f(r0.z), 0.f);
        sh[wid][c8 + 3] = fmaxf(a[3] + bf2f(r0.w), 0.f);
        sh[wid][c8 + 4] = fmaxf(a[4] + bf2f(r1.x), 0.f);
        sh[wid][c8 + 5] = fmaxf(a[5] + bf2f(r1.y), 0.f);
        sh[wid][c8 + 6] = fmaxf(a[6] + bf2f(r1.z), 0.f);
        sh[wid][c8 + 7] = fmaxf(a[7] + bf2f(r1.w), 0.f);
    }
    __syncthreads();
    float logit = 0.f;
    if (lane < 21) {
        logit = fcb[lane];
#pragma unroll
        for (int k = 0; k < 128; ++k) logit += sh[wid][k] * fcw[k * 21 + lane];
    }
    float v = (lane < 21) ? logit : -INFINITY;
#pragma unroll
    for (int off = 32; off; off >>= 1) v = fmaxf(v, __shfl_xor(v, off));
    float mx = v;
    float ex = (lane < 21) ? expf(logit - mx) : 0.f;
#pragma unroll
    for (int off = 32; off; off >>= 1) ex += __shfl_xor(ex, off);
    if (lane < 21) out[(size_t)n * 21 + lane] = logit - mx - logf(ex);
}

// Incremental layer-2 aggregate (fallback path, unchanged).
__global__ __launch_bounds__(128) void agg2_inc(
    const unsigned short* __restrict__ H2q, float* __restrict__ h2acc,
    unsigned short* __restrict__ h2b, const int* __restrict__ base,
    const int* __restrict__ elist, int r, int last)
{
    int n = blockIdx.x, t = threadIdx.x;
    int seg = n * 3 + r;
    int st = base[seg], len = base[seg + 1] - st;
    float norm = 1.0f / (float)(len > 0 ? len : 1);
    float4 s = make_float4(0.f, 0.f, 0.f, 0.f);
    for (int i = 0; i < len; ++i) {
        int sx = elist[st + i];
        ushort4 v = *(const ushort4*)&H2q[(size_t)sx * 512 + t * 4];
        s.x += bf2f(v.x); s.y += bf2f(v.y); s.z += bf2f(v.z); s.w += bf2f(v.w);
    }
    float4 a = *(const float4*)&h2acc[(size_t)n * 512 + t * 4];
    a.x += s.x * norm; a.y += s.y * norm; a.z += s.z * norm; a.w += s.w * norm;
    if (!last) {
        *(float4*)&h2acc[(size_t)n * 512 + t * 4] = a;
    } else {
        ushort4 o;
        o.x = f2bf(fmaxf(a.x, 0.f)); o.y = f2bf(fmaxf(a.y, 0.f));
        o.z = f2bf(fmaxf(a.z, 0.f)); o.w = f2bf(fmaxf(a.w, 0.f));
        *(ushort4*)&h2b[(size_t)n * 512 + t * 4] = o;
    }
}

// ---------------------------------------------------------------------------
// MFMA GEMM (proven structure, OPERAND-SWAPPED): C = A[M,K] @ Bt[Nout,K]^T.
// mfma(bfv, af) transposes the D-mapping: lane owns row = l&15 and 4
// CONSECUTIVE cols = (l>>4)*4 + rr -> 8B bf16 / 16B f32 stores.
// 128x128 tile, BK=64, 4 waves, XOR-swizzled LDS, global_load_lds x16,
// XCD-stripe swizzled 1-D grid.
// ---------------------------------------------------------------------------
__global__ __launch_bounds__(256) void gemm_mfma(
    const unsigned short* __restrict__ A, const unsigned short* __restrict__ Bt,
    const float* __restrict__ bias, void* __restrict__ C,
    int Nout, int K, int flags, int lgGX)
{
    __shared__ short __align__(16) As[8192];
    __shared__ short __align__(16) Bs[8192];
    const int tid = threadIdx.x;
    const int w = tid >> 6, l = tid & 63;

    const int nblk = (int)gridDim.x;
    const int q = nblk >> 3, rem = nblk & 7;
    const int xcd = blockIdx.x & 7, local = blockIdx.x >> 3;
    const int id2 = xcd * q + (xcd < rem ? xcd : rem) + local;
    const int row0 = (id2 >> lgGX) * 128;
    const int col0 = (id2 & ((1 << lgGX) - 1)) * 128;

    const int wm = w >> 1, wn = w & 1;
    const int lr = l >> 3, lc = l & 7;

    f32x4 acc[4][4];
#pragma unroll
    for (int i = 0; i < 4; ++i)
#pragma unroll
        for (int j = 0; j < 4; ++j) acc[i][j] = (f32x4){0.f, 0.f, 0.f, 0.f};

    for (int k0 = 0; k0 < K; k0 += 64) {
        __syncthreads();
#pragma unroll
        for (int i = 0; i < 4; ++i) {
            const int c  = i * 4 + w;
            const int r  = c * 8 + lr;
            const int c8 = lc ^ (r & 7);
            __builtin_amdgcn_global_load_lds(
                (const __attribute__((address_space(1))) void*)
                    (A + (size_t)(row0 + r) * K + k0 + c8 * 8),
                (__attribute__((address_space(3))) void*)(As + c * 512),
                16, 0, 0);
            __builtin_amdgcn_global_load_lds(
                (const __attribute__((address_space(1))) void*)
                    (Bt + (size_t)(col0 + r) * K + k0 + c8 * 8),
                (__attribute__((address_space(3))) void*)(Bs + c * 512),
                16, 0, 0);
        }
        __syncthreads();
#pragma unroll
        for (int ks = 0; ks < 2; ++ks) {
            bf16x8 af[4], bfv[4];
#pragma unroll
            for (int mf = 0; mf < 4; ++mf) {
                int r = wm * 64 + mf * 16 + (l & 15);
                int byt = (r * 128 + ks * 64 + (l >> 4) * 16) ^ ((r & 7) << 4);
                af[mf] = *(const bf16x8*)((const char*)As + byt);
            }
#pragma unroll
            for (int nf = 0; nf < 4; ++nf) {
                int r = wn * 64 + nf * 16 + (l & 15);
                int byt = (r * 128 + ks * 64 + (l >> 4) * 16) ^ ((r & 7) << 4);
                bfv[nf] = *(const bf16x8*)((const char*)Bs + byt);
            }
#pragma unroll
            for (int mf = 0; mf < 4; ++mf)
#pragma unroll
                for (int nf = 0; nf < 4; ++nf)
                    acc[mf][nf] = __builtin_amdgcn_mfma_f32_16x16x32_bf16(
                        bfv[nf], af[mf], acc[mf][nf], 0, 0, 0);
        }
    }

    // epilogue: swapped mapping -> row = l&15, cols = (l>>4)*4 + rr (consecutive)
    const int lm = l & 15;
    const int ln = (l >> 4) * 4;
#pragma unroll
    for (int mf = 0; mf < 4; ++mf) {
        int row = row0 + wm * 64 + mf * 16 + lm;
#pragma unroll
        for (int nf = 0; nf < 4; ++nf) {
            int colb = col0 + wn * 64 + nf * 16 + ln;
            float v0 = acc[mf][nf][0], v1 = acc[mf][nf][1];
            float v2 = acc[mf][nf][2], v3 = acc[mf][nf][3];
            if (flags & GF_BIAS) {
                float4 bv = *(const float4*)&bias[colb];
                v0 += bv.x; v1 += bv.y; v2 += bv.z; v3 += bv.w;
            }
            if (flags & GF_RELU) {
                v0 = fmaxf(v0, 0.f); v1 = fmaxf(v1, 0.f);
                v2 = fmaxf(v2, 0.f); v3 = fmaxf(v3, 0.f);
            }
            size_t idx = (size_t)row * Nout + colb;
            if (flags & GF_BF16) {
                uint2 pk;
                pk.x = (unsigned)f2bf(v0) | ((unsigned)f2bf(v1) << 16);
                pk.y = (unsigned)f2bf(v2) | ((unsigned)f2bf(v3) << 16);
                *(uint2*)((unsigned short*)C + idx) = pk;
            } else {
                float4 o;
                o.x = v0; o.y = v1; o.z = v2; o.w = v3;
                *(float4*)((float*)C + idx) = o;
            }
        }
    }
}

extern "C" void kernel_launch(void* const* d_in, const int* in_sizes, int n_in,
                              void* d_out, int out_size, void* d_ws, size_t ws_size,
                              hipStream_t stream)
{
    const float* x     = (const float*)d_in[0];
    const int*   ei    = (const int*)d_in[1];
    const int*   etp   = (const int*)d_in[2];
    const float* W1    = (const float*)d_in[3];
    const float* root1 = (const float*)d_in[4];
    const float* b1    = (const float*)d_in[5];
    const float* W2    = (const float*)d_in[6];
    const float* root2 = (const float*)d_in[7];
    const float* b2    = (const float*)d_in[8];
    const float* W3    = (const float*)d_in[9];
    const float* root3 = (const float*)d_in[10];
    const float* b3    = (const float*)d_in[11];
    const float* fcw   = (const float*)d_in[12];
    const float* fcb   = (const float*)d_in[13];
    float* out = (float*)d_out;
    (void)n_in; (void)out_size;

    const int N   = in_sizes[0] / 256;           // 40000
    const int E   = in_sizes[2];                 // 500000
    const int S   = N * 3;
    const int NP  = (N + 127) / 128 * 128;       // 40064
    const int GY  = NP / 128;                    // 313
    const int NB  = (S + 255) / 256;
    const int* srcp = ei;
    const int* dstp = ei + E;

    const size_t SZ_X1024 = (size_t)NP * 1024 * 2;   // 82,051,072
    const size_t SZ_X512b = (size_t)NP * 512 * 2;    // 41,025,536
    const size_t SZ_X2048 = (size_t)NP * 2048 * 2;   // 164,102,144

    // ---- fixed region ----
    char* ws = (char*)d_ws;
    int*            cnt   = (int*)(ws + 0);                  //   480,256
    int*            base  = (int*)(ws + 480256);             //   480,256 (S+1 ints)
    int*            elist = (int*)(ws + 960512);             // 2,000,000
    float*          b2cat = (float*)(ws + 2960512);          //     8,192
    float*          b3cat = (float*)(ws + 2968704);          //     2,048
    unsigned short* W3cat = (unsigned short*)(ws + 2970752); //   524,288
    unsigned short* W2cat = (unsigned short*)(ws + 3495040); // 4,194,304
    const size_t fixed_end = 7689344;
    const size_t FUSED_NEED = 7692288 + SZ_X2048 + SZ_X1024; // 253,845,504 (proven)
    const bool fused = ws_size >= FUSED_NEED;

    char* arena;
    unsigned short *W1t, *xb, *Xcat, *h1b, *H2all, *H2q, *h2b, *H3cat;
    float* h2acc;
    if (fused) {
        arena = ws + 7692288;
        Xcat  = (unsigned short*)(arena);
        W1t   = (unsigned short*)(arena + SZ_X1024);             // dead before GEMM2
        xb    = (unsigned short*)(arena + SZ_X1024 + 2097152);   // dead before GEMM2
        h1b   = (unsigned short*)(arena + SZ_X2048);
        H2all = (unsigned short*)(arena);                        // after GEMM1
        h2b   = (unsigned short*)(arena + SZ_X2048);             // over h1b
        H3cat = (unsigned short*)(arena);                        // after agg2
        H2q = nullptr; h2acc = nullptr;
    } else {
        W1t   = (unsigned short*)(ws + fixed_end);               // 2,097,152
        arena = ws + 9789440;                                    // 4096-aligned
        Xcat  = (unsigned short*)(arena);
        h2acc = (float*)(arena);                                 // after GEMM1
        h1b   = (unsigned short*)(arena + SZ_X1024);
        h2b   = (unsigned short*)(arena + SZ_X1024);             // over h1b
        H3cat = (unsigned short*)(arena + SZ_X1024 + SZ_X512b);
        xb    = (unsigned short*)(arena + 2 * SZ_X1024);         // pre-layer1 only
        H2q   = (unsigned short*)(arena + 2 * SZ_X1024);
        H2all = nullptr;
    }
    int* bsum = (int*)(arena);          // scan scratch, dead before agg1

    // ---- CSR build: zero -> count -> scan -> fill (fill restores cnt to 0) ----
    zero_kernel<<<(30016 + 255) / 256, 256, 0, stream>>>((float*)cnt, 30016);
    count_kernel<<<(E + 255) / 256, 256, 0, stream>>>(dstp, etp, cnt, E);
    scanA<<<NB, 256, 0, stream>>>(cnt, base, bsum, S);
    scanB<<<1, 512, 0, stream>>>(bsum, NB);
    scanC<<<NB, 256, 0, stream>>>(base, bsum, S);
    fill_kernel<<<(E + 255) / 256, 256, 0, stream>>>(srcp, dstp, etp, base, cnt, elist, E, S);

    // ---- weights / bias prep (tiled coalesced transposes) ----
    tr1_tiled<<<1024, 256, 0, stream>>>(W1, root1, W1t);
    tr2_tiled<<<2048, 256, 0, stream>>>(root2, W2, W2cat);
    tr3_tiled<<<256, 256, 0, stream>>>(root3, W3, W3cat);
    bias_cat<<<10, 256, 0, stream>>>(b2cat, b3cat, b2, b3);
    conv_bf16<<<(int)(((long)N * 32 + 255) / 256), 256, 0, stream>>>(x, xb, (long)N * 32);

    // ---- layer 1 ----
    agg1_kernel<<<N, 256, 0, stream>>>(xb, base, elist, Xcat);
    gemm_mfma<<<8 * GY, 256, 0, stream>>>(
        Xcat, W1t, b1, h1b, 1024, 1024, GF_BIAS | GF_RELU | GF_BF16, 3);

    // ---- layer 2 ----
    if (fused) {
        gemm_mfma<<<16 * GY, 256, 0, stream>>>(
            h1b, W2cat, b2cat, H2all, 2048, 1024, GF_BIAS | GF_BF16, 4);
        agg2_fused<<<N / 4, 256, 0, stream>>>(H2all, h2b, base, elist);
    } else {
        gemm_mfma<<<4 * GY, 256, 0, stream>>>(
            h1b, W2cat, b2, h2acc, 512, 1024, GF_BIAS, 2);
        for (int r = 0; r < 3; ++r) {
            gemm_mfma<<<4 * GY, 256, 0, stream>>>(
                h1b, W2cat + (size_t)(1 + r) * 524288, nullptr, H2q, 512, 1024, GF_BF16, 2);
            agg2_inc<<<N, 128, 0, stream>>>(H2q, h2acc, h2b, base, elist, r, r == 2);
        }
    }

    // ---- layer 3 (fused root+relations) + head ----
    gemm_mfma<<<4 * GY, 256, 0, stream>>>(
        h2b, W3cat, b3cat, H3cat, 512, 512, GF_BIAS | GF_BF16, 2);
    agg3_head<<<N / 4, 256, 0, stream>>>(H3cat, fcw, fcb, base, elist, out);
}

// Round 12
// 626.362 us; speedup vs baseline: 1.1031x; 1.1031x over previous
//
#include <hip/hip_runtime.h>
#include <cstdint>
#include <cstddef>

// ---------------------------------------------------------------------------
// RGCN 3-layer + FC head. 128x128/4-wave bf16 MFMA GEMM (round-9 proven
// structure, 84 VGPR, ~3 blocks/CU) + CSR gather aggregation (flattened
// per-node edge loop, 16B/lane loads). ws peak = 253,845,504 B (proven).
// ---------------------------------------------------------------------------

typedef short bf16x8 __attribute__((ext_vector_type(8)));
typedef float f32x4 __attribute__((ext_vector_type(4)));

#define GF_BIAS 1
#define GF_RELU 2
#define GF_BF16 4

__device__ __forceinline__ unsigned short f2bf(float f) {
    unsigned u = __float_as_uint(f);
    return (unsigned short)((u + 0x7FFFu + ((u >> 16) & 1u)) >> 16);
}
__device__ __forceinline__ float bf2f(unsigned short h) {
    return __uint_as_float((unsigned)h << 16);
}

__global__ __launch_bounds__(256) void zero_kernel(float* __restrict__ p, long n4)
{
    long i = (long)blockIdx.x * 256 + threadIdx.x;
    if (i < n4) ((float4*)p)[i] = make_float4(0.f, 0.f, 0.f, 0.f);
}

__global__ __launch_bounds__(256) void count_kernel(
    const int* __restrict__ dst, const int* __restrict__ et,
    int* __restrict__ cnt, int E)
{
    int e = blockIdx.x * 256 + threadIdx.x;
    if (e < E) atomicAdd(&cnt[dst[e] * 3 + et[e]], 1);
}

// ---- 2-level exclusive scan over S ints ----
__global__ __launch_bounds__(256) void scanA(
    const int* __restrict__ cnt, int* __restrict__ base,
    int* __restrict__ bsum, int S)
{
    __shared__ int sh[256];
    int i = blockIdx.x * 256 + threadIdx.x;
    int v = (i < S) ? cnt[i] : 0;
    sh[threadIdx.x] = v;
    __syncthreads();
#pragma unroll
    for (int off = 1; off < 256; off <<= 1) {
        int t = (threadIdx.x >= off) ? sh[threadIdx.x - off] : 0;
        __syncthreads();
        sh[threadIdx.x] += t;
        __syncthreads();
    }
    if (i < S) base[i] = sh[threadIdx.x] - v;
    if (threadIdx.x == 255) bsum[blockIdx.x] = sh[255];
}

__global__ __launch_bounds__(512) void scanB(int* __restrict__ bsum, int NB)
{
    __shared__ int sh[512];
    int t = threadIdx.x;
    int v = (t < NB) ? bsum[t] : 0;
    sh[t] = v;
    __syncthreads();
#pragma unroll
    for (int off = 1; off < 512; off <<= 1) {
        int u = (t >= off) ? sh[t - off] : 0;
        __syncthreads();
        sh[t] += u;
        __syncthreads();
    }
    if (t < NB) bsum[t] = sh[t] - v;
}

__global__ __launch_bounds__(256) void scanC(
    int* __restrict__ base, const int* __restrict__ bsum, int S)
{
    int i = blockIdx.x * 256 + threadIdx.x;
    if (i < S) base[i] += bsum[blockIdx.x];
}

// fill: decrements cnt back to zero; writes base[S] = E sentinel.
__global__ __launch_bounds__(256) void fill_kernel(
    const int* __restrict__ src, const int* __restrict__ dst,
    const int* __restrict__ et, int* __restrict__ base,
    int* __restrict__ cnt, int* __restrict__ elist, int E, int S)
{
    int e = blockIdx.x * 256 + threadIdx.x;
    if (e == 0) base[S] = E;
    if (e >= E) return;
    int seg = dst[e] * 3 + et[e];
    int old = atomicSub(&cnt[seg], 1);
    elist[base[seg] + old - 1] = src[e];
}

// ---- tiled coalesced transposes (f32 -> bf16, out[j][k] = src[k][j]) ----
__global__ __launch_bounds__(256) void tr1_tiled(
    const float* __restrict__ W1, const float* __restrict__ root1,
    unsigned short* __restrict__ W1t)
{
    __shared__ float sh[32][33];
    int bk = blockIdx.x & 31, bj = blockIdx.x >> 5;
    int tc = threadIdx.x & 31, tr = threadIdx.x >> 5;
    int k0 = bk * 32, j0 = bj * 32;
#pragma unroll
    for (int i = 0; i < 4; ++i) {
        int k = k0 + tr + i * 8;
        float v = (k < 768) ? W1[(size_t)k * 1024 + j0 + tc]
                            : root1[(size_t)(k - 768) * 1024 + j0 + tc];
        sh[tr + i * 8][tc] = v;
    }
    __syncthreads();
#pragma unroll
    for (int i = 0; i < 4; ++i)
        W1t[(size_t)(j0 + tr + i * 8) * 1024 + k0 + tc] = f2bf(sh[tc][tr + i * 8]);
}

__global__ __launch_bounds__(256) void tr2_tiled(
    const float* __restrict__ root2, const float* __restrict__ W2,
    unsigned short* __restrict__ W2cat)
{
    __shared__ float sh[32][33];
    int bk = blockIdx.x & 31, br = blockIdx.x >> 5;
    int tc = threadIdx.x & 31, tr = threadIdx.x >> 5;
    int k0 = bk * 32, r0 = br * 32;
    int s = r0 >> 9, j0 = r0 & 511;
    const float* src = (s == 0) ? root2 : W2 + (size_t)(s - 1) * 524288;
#pragma unroll
    for (int i = 0; i < 4; ++i)
        sh[tr + i * 8][tc] = src[(size_t)(k0 + tr + i * 8) * 512 + j0 + tc];
    __syncthreads();
#pragma unroll
    for (int i = 0; i < 4; ++i)
        W2cat[(size_t)(r0 + tr + i * 8) * 1024 + k0 + tc] = f2bf(sh[tc][tr + i * 8]);
}

__global__ __launch_bounds__(256) void tr3_tiled(
    const float* __restrict__ root3, const float* __restrict__ W3,
    unsigned short* __restrict__ W3cat)
{
    __shared__ float sh[32][33];
    int bk = blockIdx.x & 15, br = blockIdx.x >> 4;
    int tc = threadIdx.x & 31, tr = threadIdx.x >> 5;
    int k0 = bk * 32, r0 = br * 32;
    int s = r0 >> 7, j0 = r0 & 127;
    const float* src = (s == 0) ? root3 : W3 + (size_t)(s - 1) * 65536;
#pragma unroll
    for (int i = 0; i < 4; ++i)
        sh[tr + i * 8][tc] = src[(size_t)(k0 + tr + i * 8) * 128 + j0 + tc];
    __syncthreads();
#pragma unroll
    for (int i = 0; i < 4; ++i)
        W3cat[(size_t)(r0 + tr + i * 8) * 512 + k0 + tc] = f2bf(sh[tc][tr + i * 8]);
}

__global__ __launch_bounds__(256) void bias_cat(
    float* __restrict__ b2cat, float* __restrict__ b3cat,
    const float* __restrict__ b2, const float* __restrict__ b3)
{
    int i = blockIdx.x * 256 + threadIdx.x;
    if (i < 2048) b2cat[i] = (i < 512) ? b2[i] : 0.f;
    else if (i < 2560) { int j = i - 2048; b3cat[j] = (j < 128) ? b3[j] : 0.f; }
}

__global__ __launch_bounds__(256) void conv_bf16(
    const float* __restrict__ s, unsigned short* __restrict__ d, long n8)
{
    long i = (long)blockIdx.x * 256 + threadIdx.x;
    if (i >= n8) return;
    const float* p = s + i * 8;
    float4 a = *(const float4*)p, b = *(const float4*)(p + 4);
    ushort4 o0, o1;
    o0.x = f2bf(a.x); o0.y = f2bf(a.y); o0.z = f2bf(a.z); o0.w = f2bf(a.w);
    o1.x = f2bf(b.x); o1.y = f2bf(b.y); o1.z = f2bf(b.z); o1.w = f2bf(b.w);
    *(ushort4*)(d + i * 8) = o0;
    *(ushort4*)(d + i * 8 + 4) = o1;
}

// Layer-1 aggregate: block = 4 waves, node n. Waves 0-2: relation w via two
// 32-lane groups (2 edges in flight, 16B/lane), fold with shfl_xor(32).
__global__ __launch_bounds__(256) void agg1_kernel(
    const unsigned short* __restrict__ xb, const int* __restrict__ base,
    const int* __restrict__ elist, unsigned short* __restrict__ Xcat)
{
    int n = blockIdx.x;
    int w = threadIdx.x >> 6, l = threadIdx.x & 63;
    if (w == 3) {
        *(ushort4*)&Xcat[(size_t)n * 1024 + 768 + l * 4] =
            *(const ushort4*)&xb[(size_t)n * 256 + l * 4];
        return;
    }
    int seg = n * 3 + w;
    int st = base[seg], len = base[seg + 1] - st;
    float norm = 1.0f / (float)(len > 0 ? len : 1);
    int g = l >> 5, c8 = (l & 31) * 8;
    float a[8];
#pragma unroll
    for (int j = 0; j < 8; ++j) a[j] = 0.f;
    for (int i = g; i < len; i += 2) {
        const unsigned short* q = xb + (size_t)elist[st + i] * 256 + c8;
        ushort4 v0 = *(const ushort4*)q;
        ushort4 v1 = *(const ushort4*)(q + 4);
        a[0] += bf2f(v0.x); a[1] += bf2f(v0.y); a[2] += bf2f(v0.z); a[3] += bf2f(v0.w);
        a[4] += bf2f(v1.x); a[5] += bf2f(v1.y); a[6] += bf2f(v1.z); a[7] += bf2f(v1.w);
    }
#pragma unroll
    for (int j = 0; j < 8; ++j) a[j] += __shfl_xor(a[j], 32);
    if (l < 32) {
        ushort4 o0, o1;
        o0.x = f2bf(a[0] * norm); o0.y = f2bf(a[1] * norm);
        o0.z = f2bf(a[2] * norm); o0.w = f2bf(a[3] * norm);
        o1.x = f2bf(a[4] * norm); o1.y = f2bf(a[5] * norm);
        o1.z = f2bf(a[6] * norm); o1.w = f2bf(a[7] * norm);
        unsigned short* d = Xcat + (size_t)n * 1024 + w * 256 + c8;
        *(ushort4*)d = o0;
        *(ushort4*)(d + 4) = o1;
    }
}

// Fused layer-2 aggregate over H2all [NP][2048] (root | r0 | r1 | r2).
// Block = 4 waves = 4 nodes; lane owns 8 cols (16B). FLATTENED edge loop.
__global__ __launch_bounds__(256) void agg2_fused(
    const unsigned short* __restrict__ H2all, unsigned short* __restrict__ h2b,
    const int* __restrict__ base, const int* __restrict__ elist)
{
    int w = threadIdx.x >> 6, l = threadIdx.x & 63;
    int n = blockIdx.x * 4 + w;
    int c8 = l * 8;
    const unsigned short* rowN = H2all + (size_t)n * 2048 + c8;
    float a[8];
    {
        ushort4 r0 = *(const ushort4*)rowN;
        ushort4 r1 = *(const ushort4*)(rowN + 4);
        a[0] = bf2f(r0.x); a[1] = bf2f(r0.y); a[2] = bf2f(r0.z); a[3] = bf2f(r0.w);
        a[4] = bf2f(r1.x); a[5] = bf2f(r1.y); a[6] = bf2f(r1.z); a[7] = bf2f(r1.w);
    }
    int s0 = base[n * 3], s1b = base[n * 3 + 1];
    int s2b = base[n * 3 + 2], s3 = base[n * 3 + 3];
    int l0 = s1b - s0, l1 = s2b - s1b, l2 = s3 - s2b;
    float nm0 = 1.f / (float)(l0 > 0 ? l0 : 1);
    float nm1 = 1.f / (float)(l1 > 0 ? l1 : 1);
    float nm2 = 1.f / (float)(l2 > 0 ? l2 : 1);
    int i = s0;
    for (; i + 2 <= s3; i += 2) {
        int ia = i, ib = i + 1;
        int ra = (ia >= s1b) + (ia >= s2b);
        int rb = (ib >= s1b) + (ib >= s2b);
        float wa = (ia < s1b) ? nm0 : ((ia < s2b) ? nm1 : nm2);
        float wb = (ib < s1b) ? nm0 : ((ib < s2b) ? nm1 : nm2);
        const unsigned short* qa =
            H2all + (size_t)elist[ia] * 2048 + 512 * (1 + ra) + c8;
        const unsigned short* qb =
            H2all + (size_t)elist[ib] * 2048 + 512 * (1 + rb) + c8;
        ushort4 u0 = *(const ushort4*)qa, u1 = *(const ushort4*)(qa + 4);
        ushort4 v0 = *(const ushort4*)qb, v1 = *(const ushort4*)(qb + 4);
        a[0] += bf2f(u0.x) * wa + bf2f(v0.x) * wb;
        a[1] += bf2f(u0.y) * wa + bf2f(v0.y) * wb;
        a[2] += bf2f(u0.z) * wa + bf2f(v0.z) * wb;
        a[3] += bf2f(u0.w) * wa + bf2f(v0.w) * wb;
        a[4] += bf2f(u1.x) * wa + bf2f(v1.x) * wb;
        a[5] += bf2f(u1.y) * wa + bf2f(v1.y) * wb;
        a[6] += bf2f(u1.z) * wa + bf2f(v1.z) * wb;
        a[7] += bf2f(u1.w) * wa + bf2f(v1.w) * wb;
    }
    if (i < s3) {
        int r = (i >= s1b) + (i >= s2b);
        float wN = (i < s1b) ? nm0 : ((i < s2b) ? nm1 : nm2);
        const unsigned short* q =
            H2all + (size_t)elist[i] * 2048 + 512 * (1 + r) + c8;
        ushort4 u0 = *(const ushort4*)q, u1 = *(const ushort4*)(q + 4);
        a[0] += bf2f(u0.x) * wN; a[1] += bf2f(u0.y) * wN;
        a[2] += bf2f(u0.z) * wN; a[3] += bf2f(u0.w) * wN;
        a[4] += bf2f(u1.x) * wN; a[5] += bf2f(u1.y) * wN;
        a[6] += bf2f(u1.z) * wN; a[7] += bf2f(u1.w) * wN;
    }
    ushort4 o0, o1;
    o0.x = f2bf(fmaxf(a[0], 0.f)); o0.y = f2bf(fmaxf(a[1], 0.f));
    o0.z = f2bf(fmaxf(a[2], 0.f)); o0.w = f2bf(fmaxf(a[3], 0.f));
    o1.x = f2bf(fmaxf(a[4], 0.f)); o1.y = f2bf(fmaxf(a[5], 0.f));
    o1.z = f2bf(fmaxf(a[6], 0.f)); o1.w = f2bf(fmaxf(a[7], 0.f));
    unsigned short* d = h2b + (size_t)n * 512 + c8;
    *(ushort4*)d = o0;
    *(ushort4*)(d + 4) = o1;
}

// Fused layer-3 aggregate + FC head. Block = 4 waves = 4 nodes. FLATTENED
// edge loop over 4 lane-groups of 16 (16B/lane), fold shfl_xor(16,32).
__global__ __launch_bounds__(256) void agg3_head(
    const unsigned short* __restrict__ H3cat, const float* __restrict__ fcw,
    const float* __restrict__ fcb, const int* __restrict__ base,
    const int* __restrict__ elist, float* __restrict__ out)
{
    __shared__ float sh[4][128];
    int wid = threadIdx.x >> 6, lane = threadIdx.x & 63;
    int n = blockIdx.x * 4 + wid;
    int g = lane >> 4, c8 = (lane & 15) * 8;
    int s0 = base[n * 3], s1b = base[n * 3 + 1];
    int s2b = base[n * 3 + 2], s3 = base[n * 3 + 3];
    int l0 = s1b - s0, l1 = s2b - s1b, l2 = s3 - s2b;
    float nm0 = 1.f / (float)(l0 > 0 ? l0 : 1);
    float nm1 = 1.f / (float)(l1 > 0 ? l1 : 1);
    float nm2 = 1.f / (float)(l2 > 0 ? l2 : 1);
    float a[8];
#pragma unroll
    for (int j = 0; j < 8; ++j) a[j] = 0.f;
    for (int i = s0 + g; i < s3; i += 4) {
        int r = (i >= s1b) + (i >= s2b);
        float wN = (i < s1b) ? nm0 : ((i < s2b) ? nm1 : nm2);
        const unsigned short* q =
            H3cat + (size_t)elist[i] * 512 + 128 * (1 + r) + c8;
        ushort4 u0 = *(const ushort4*)q, u1 = *(const ushort4*)(q + 4);
        a[0] += bf2f(u0.x) * wN; a[1] += bf2f(u0.y) * wN;
        a[2] += bf2f(u0.z) * wN; a[3] += bf2f(u0.w) * wN;
        a[4] += bf2f(u1.x) * wN; a[5] += bf2f(u1.y) * wN;
        a[6] += bf2f(u1.z) * wN; a[7] += bf2f(u1.w) * wN;
    }
#pragma unroll
    for (int j = 0; j < 8; ++j) {
        a[j] += __shfl_xor(a[j], 16);
        a[j] += __shfl_xor(a[j], 32);
    }
    if (lane < 16) {
        const unsigned short* rt = H3cat + (size_t)n * 512 + c8;
        ushort4 r0 = *(const ushort4*)rt, r1 = *(const ushort4*)(rt + 4);
        sh[wid][c8 + 0] = fmaxf(a[0] + bf2f(r0.x), 0.f);
        sh[wid][c8 + 1] = fmaxf(a[1] + bf2f(r0.y), 0.f);
        sh[wid][c8 + 2] = fmaxf(a[2] + bf2f(r0.z), 0.f);
        sh[wid][c8 + 3] = fmaxf(a[3] + bf2f(r0.w), 0.f);
        sh[wid][c8 + 4] = fmaxf(a[4] + bf2f(r1.x), 0.f);
        sh[wid][c8 + 5] = fmaxf(a[5] + bf2f(r1.y), 0.f);
        sh[wid][c8 + 6] = fmaxf(a[6] + bf2f(r1.z), 0.f);
        sh[wid][c8 + 7] = fmaxf(a[7] + bf2f(r1.w), 0.f);
    }
    __syncthreads();
    float logit = 0.f;
    if (lane < 21) {
        logit = fcb[lane];
#pragma unroll
        for (int k = 0; k < 128; ++k) logit += sh[wid][k] * fcw[k * 21 + lane];
    }
    float v = (lane < 21) ? logit : -INFINITY;
#pragma unroll
    for (int off = 32; off; off >>= 1) v = fmaxf(v, __shfl_xor(v, off));
    float mx = v;
    float ex = (lane < 21) ? expf(logit - mx) : 0.f;
#pragma unroll
    for (int off = 32; off; off >>= 1) ex += __shfl_xor(ex, off);
    if (lane < 21) out[(size_t)n * 21 + lane] = logit - mx - logf(ex);
}

// Incremental layer-2 aggregate (fallback path, unchanged).
__global__ __launch_bounds__(128) void agg2_inc(
    const unsigned short* __restrict__ H2q, float* __restrict__ h2acc,
    unsigned short* __restrict__ h2b, const int* __restrict__ base,
    const int* __restrict__ elist, int r, int last)
{
    int n = blockIdx.x, t = threadIdx.x;
    int seg = n * 3 + r;
    int st = base[seg], len = base[seg + 1] - st;
    float norm = 1.0f / (float)(len > 0 ? len : 1);
    float4 s = make_float4(0.f, 0.f, 0.f, 0.f);
    for (int i = 0; i < len; ++i) {
        int sx = elist[st + i];
        ushort4 v = *(const ushort4*)&H2q[(size_t)sx * 512 + t * 4];
        s.x += bf2f(v.x); s.y += bf2f(v.y); s.z += bf2f(v.z); s.w += bf2f(v.w);
    }
    float4 a = *(const float4*)&h2acc[(size_t)n * 512 + t * 4];
    a.x += s.x * norm; a.y += s.y * norm; a.z += s.z * norm; a.w += s.w * norm;
    if (!last) {
        *(float4*)&h2acc[(size_t)n * 512 + t * 4] = a;
    } else {
        ushort4 o;
        o.x = f2bf(fmaxf(a.x, 0.f)); o.y = f2bf(fmaxf(a.y, 0.f));
        o.z = f2bf(fmaxf(a.z, 0.f)); o.w = f2bf(fmaxf(a.w, 0.f));
        *(ushort4*)&h2b[(size_t)n * 512 + t * 4] = o;
    }
}

// ---------------------------------------------------------------------------
// MFMA GEMM (round-9 proven, 84 VGPR): C = A[M,K](bf16) @ Bt[Nout,K]^T.
// 128x128 tile, BK=64, 4 waves, XOR-swizzled LDS, global_load_lds x16,
// XCD-stripe swizzled 1-D grid. Do NOT touch: on an occupancy cliff
// (round 11: +12 VGPR for a fancier epilogue cost 23%).
// ---------------------------------------------------------------------------
__global__ __launch_bounds__(256) void gemm_mfma(
    const unsigned short* __restrict__ A, const unsigned short* __restrict__ Bt,
    const float* __restrict__ bias, void* __restrict__ C,
    int Nout, int K, int flags, int lgGX)
{
    __shared__ short __align__(16) As[8192];
    __shared__ short __align__(16) Bs[8192];
    const int tid = threadIdx.x;
    const int w = tid >> 6, l = tid & 63;

    const int nblk = (int)gridDim.x;
    const int q = nblk >> 3, rem = nblk & 7;
    const int xcd = blockIdx.x & 7, local = blockIdx.x >> 3;
    const int id2 = xcd * q + (xcd < rem ? xcd : rem) + local;
    const int row0 = (id2 >> lgGX) * 128;
    const int col0 = (id2 & ((1 << lgGX) - 1)) * 128;

    const int wm = w >> 1, wn = w & 1;
    const int lr = l >> 3, lc = l & 7;

    f32x4 acc[4][4];
#pragma unroll
    for (int i = 0; i < 4; ++i)
#pragma unroll
        for (int j = 0; j < 4; ++j) acc[i][j] = (f32x4){0.f, 0.f, 0.f, 0.f};

    for (int k0 = 0; k0 < K; k0 += 64) {
        __syncthreads();
#pragma unroll
        for (int i = 0; i < 4; ++i) {
            const int c  = i * 4 + w;
            const int r  = c * 8 + lr;
            const int c8 = lc ^ (r & 7);
            __builtin_amdgcn_global_load_lds(
                (const __attribute__((address_space(1))) void*)
                    (A + (size_t)(row0 + r) * K + k0 + c8 * 8),
                (__attribute__((address_space(3))) void*)(As + c * 512),
                16, 0, 0);
            __builtin_amdgcn_global_load_lds(
                (const __attribute__((address_space(1))) void*)
                    (Bt + (size_t)(col0 + r) * K + k0 + c8 * 8),
                (__attribute__((address_space(3))) void*)(Bs + c * 512),
                16, 0, 0);
        }
        __syncthreads();
#pragma unroll
        for (int ks = 0; ks < 2; ++ks) {
            bf16x8 af[4], bfv[4];
#pragma unroll
            for (int mf = 0; mf < 4; ++mf) {
                int r = wm * 64 + mf * 16 + (l & 15);
                int byt = (r * 128 + ks * 64 + (l >> 4) * 16) ^ ((r & 7) << 4);
                af[mf] = *(const bf16x8*)((const char*)As + byt);
            }
#pragma unroll
            for (int nf = 0; nf < 4; ++nf) {
                int r = wn * 64 + nf * 16 + (l & 15);
                int byt = (r * 128 + ks * 64 + (l >> 4) * 16) ^ ((r & 7) << 4);
                bfv[nf] = *(const bf16x8*)((const char*)Bs + byt);
            }
#pragma unroll
            for (int mf = 0; mf < 4; ++mf)
#pragma unroll
                for (int nf = 0; nf < 4; ++nf)
                    acc[mf][nf] = __builtin_amdgcn_mfma_f32_16x16x32_bf16(
                        af[mf], bfv[nf], acc[mf][nf], 0, 0, 0);
        }
    }

    const int lrow = (l >> 4) * 4;
    const int lcol = l & 15;
#pragma unroll
    for (int mf = 0; mf < 4; ++mf) {
#pragma unroll
        for (int nf = 0; nf < 4; ++nf) {
            int col = col0 + wn * 64 + nf * 16 + lcol;
            float bv = (flags & GF_BIAS) ? bias[col] : 0.f;
#pragma unroll
            for (int rr = 0; rr < 4; ++rr) {
                int row = row0 + wm * 64 + mf * 16 + lrow + rr;
                float v = acc[mf][nf][rr] + bv;
                if (flags & GF_RELU) v = fmaxf(v, 0.f);
                size_t idx = (size_t)row * Nout + col;
                if (flags & GF_BF16) ((unsigned short*)C)[idx] = f2bf(v);
                else                 ((float*)C)[idx] = v;
            }
        }
    }
}

extern "C" void kernel_launch(void* const* d_in, const int* in_sizes, int n_in,
                              void* d_out, int out_size, void* d_ws, size_t ws_size,
                              hipStream_t stream)
{
    const float* x     = (const float*)d_in[0];
    const int*   ei    = (const int*)d_in[1];
    const int*   etp   = (const int*)d_in[2];
    const float* W1    = (const float*)d_in[3];
    const float* root1 = (const float*)d_in[4];
    const float* b1    = (const float*)d_in[5];
    const float* W2    = (const float*)d_in[6];
    const float* root2 = (const float*)d_in[7];
    const float* b2    = (const float*)d_in[8];
    const float* W3    = (const float*)d_in[9];
    const float* root3 = (const float*)d_in[10];
    const float* b3    = (const float*)d_in[11];
    const float* fcw   = (const float*)d_in[12];
    const float* fcb   = (const float*)d_in[13];
    float* out = (float*)d_out;
    (void)n_in; (void)out_size;

    const int N   = in_sizes[0] / 256;           // 40000
    const int E   = in_sizes[2];                 // 500000
    const int S   = N * 3;
    const int NP  = (N + 127) / 128 * 128;       // 40064
    const int GY  = NP / 128;                    // 313
    const int NB  = (S + 255) / 256;
    const int* srcp = ei;
    const int* dstp = ei + E;

    const size_t SZ_X1024 = (size_t)NP * 1024 * 2;   // 82,051,072
    const size_t SZ_X512b = (size_t)NP * 512 * 2;    // 41,025,536
    const size_t SZ_X2048 = (size_t)NP * 2048 * 2;   // 164,102,144

    // ---- fixed region ----
    char* ws = (char*)d_ws;
    int*            cnt   = (int*)(ws + 0);                  //   480,256
    int*            base  = (int*)(ws + 480256);             //   480,256 (S+1 ints)
    int*            elist = (int*)(ws + 960512);             // 2,000,000
    float*          b2cat = (float*)(ws + 2960512);          //     8,192
    float*          b3cat = (float*)(ws + 2968704);          //     2,048
    unsigned short* W3cat = (unsigned short*)(ws + 2970752); //   524,288
    unsigned short* W2cat = (unsigned short*)(ws + 3495040); // 4,194,304
    const size_t fixed_end = 7689344;
    const size_t FUSED_NEED = 7692288 + SZ_X2048 + SZ_X1024; // 253,845,504 (proven)
    const bool fused = ws_size >= FUSED_NEED;

    char* arena;
    unsigned short *W1t, *xb, *Xcat, *h1b, *H2all, *H2q, *h2b, *H3cat;
    float* h2acc;
    if (fused) {
        arena = ws + 7692288;
        Xcat  = (unsigned short*)(arena);
        W1t   = (unsigned short*)(arena + SZ_X1024);             // dead before GEMM2
        xb    = (unsigned short*)(arena + SZ_X1024 + 2097152);   // dead before GEMM2
        h1b   = (unsigned short*)(arena + SZ_X2048);
        H2all = (unsigned short*)(arena);                        // after GEMM1
        h2b   = (unsigned short*)(arena + SZ_X2048);             // over h1b
        H3cat = (unsigned short*)(arena);                        // after agg2
        H2q = nullptr; h2acc = nullptr;
    } else {
        W1t   = (unsigned short*)(ws + fixed_end);               // 2,097,152
        arena = ws + 9789440;                                    // 4096-aligned
        Xcat  = (unsigned short*)(arena);
        h2acc = (float*)(arena);                                 // after GEMM1
        h1b   = (unsigned short*)(arena + SZ_X1024);
        h2b   = (unsigned short*)(arena + SZ_X1024);             // over h1b
        H3cat = (unsigned short*)(arena + SZ_X1024 + SZ_X512b);
        xb    = (unsigned short*)(arena + 2 * SZ_X1024);         // pre-layer1 only
        H2q   = (unsigned short*)(arena + 2 * SZ_X1024);
        H2all = nullptr;
    }
    int* bsum = (int*)(arena);          // scan scratch, dead before agg1

    // ---- CSR build: zero -> count -> scan -> fill (fill restores cnt to 0) ----
    zero_kernel<<<(30016 + 255) / 256, 256, 0, stream>>>((float*)cnt, 30016);
    count_kernel<<<(E + 255) / 256, 256, 0, stream>>>(dstp, etp, cnt, E);
    scanA<<<NB, 256, 0, stream>>>(cnt, base, bsum, S);
    scanB<<<1, 512, 0, stream>>>(bsum, NB);
    scanC<<<NB, 256, 0, stream>>>(base, bsum, S);
    fill_kernel<<<(E + 255) / 256, 256, 0, stream>>>(srcp, dstp, etp, base, cnt, elist, E, S);

    // ---- weights / bias prep (tiled coalesced transposes) ----
    tr1_tiled<<<1024, 256, 0, stream>>>(W1, root1, W1t);
    tr2_tiled<<<2048, 256, 0, stream>>>(root2, W2, W2cat);
    tr3_tiled<<<256, 256, 0, stream>>>(root3, W3, W3cat);
    bias_cat<<<10, 256, 0, stream>>>(b2cat, b3cat, b2, b3);
    conv_bf16<<<(int)(((long)N * 32 + 255) / 256), 256, 0, stream>>>(x, xb, (long)N * 32);

    // ---- layer 1 ----
    agg1_kernel<<<N, 256, 0, stream>>>(xb, base, elist, Xcat);
    gemm_mfma<<<8 * GY, 256, 0, stream>>>(
        Xcat, W1t, b1, h1b, 1024, 1024, GF_BIAS | GF_RELU | GF_BF16, 3);

    // ---- layer 2 ----
    if (fused) {
        gemm_mfma<<<16 * GY, 256, 0, stream>>>(
            h1b, W2cat, b2cat, H2all, 2048, 1024, GF_BIAS | GF_BF16, 4);
        agg2_fused<<<N / 4, 256, 0, stream>>>(H2all, h2b, base, elist);
    } else {
        gemm_mfma<<<4 * GY, 256, 0, stream>>>(
            h1b, W2cat, b2, h2acc, 512, 1024, GF_BIAS, 2);
        for (int r = 0; r < 3; ++r) {
            gemm_mfma<<<4 * GY, 256, 0, stream>>>(
                h1b, W2cat + (size_t)(1 + r) * 524288, nullptr, H2q, 512, 1024, GF_BF16, 2);
            agg2_inc<<<N, 128, 0, stream>>>(H2q, h2acc, h2b, base, elist, r, r == 2);
        }
    }

    // ---- layer 3 (fused root+relations) + head ----
    gemm_mfma<<<4 * GY, 256, 0, stream>>>(
        h2b, W3cat, b3cat, H3cat, 512, 512, GF_BIAS | GF_BF16, 2);
    agg3_head<<<N / 4, 256, 0, stream>>>(H3cat, fcw, fcb, base, elist, out);
}

// Round 13
// 619.047 us; speedup vs baseline: 1.1161x; 1.0118x over previous
//
#include <hip/hip_runtime.h>
#include <cstdint>
#include <cstddef>

// ---------------------------------------------------------------------------
// RGCN 3-layer + FC head. 128x128/4-wave bf16 MFMA GEMM (round-9 proven,
// 84 VGPR — DO NOT TOUCH, occupancy cliff) + CSR gather aggregation
// (agg2: 4 waves/node + LDS fold; agg1/agg3 lane-group split) + single
// merged prep kernel. ws peak = 253,845,504 B (proven).
// ---------------------------------------------------------------------------

typedef short bf16x8 __attribute__((ext_vector_type(8)));
typedef float f32x4 __attribute__((ext_vector_type(4)));

#define GF_BIAS 1
#define GF_RELU 2
#define GF_BF16 4

__device__ __forceinline__ unsigned short f2bf(float f) {
    unsigned u = __float_as_uint(f);
    return (unsigned short)((u + 0x7FFFu + ((u >> 16) & 1u)) >> 16);
}
__device__ __forceinline__ float bf2f(unsigned short h) {
    return __uint_as_float((unsigned)h << 16);
}

__global__ __launch_bounds__(256) void zero_kernel(float* __restrict__ p, long n4)
{
    long i = (long)blockIdx.x * 256 + threadIdx.x;
    if (i < n4) ((float4*)p)[i] = make_float4(0.f, 0.f, 0.f, 0.f);
}

__global__ __launch_bounds__(256) void count_kernel(
    const int* __restrict__ dst, const int* __restrict__ et,
    int* __restrict__ cnt, int E)
{
    int e = blockIdx.x * 256 + threadIdx.x;
    if (e < E) atomicAdd(&cnt[dst[e] * 3 + et[e]], 1);
}

// ---- 2-level exclusive scan over S ints ----
__global__ __launch_bounds__(256) void scanA(
    const int* __restrict__ cnt, int* __restrict__ base,
    int* __restrict__ bsum, int S)
{
    __shared__ int sh[256];
    int i = blockIdx.x * 256 + threadIdx.x;
    int v = (i < S) ? cnt[i] : 0;
    sh[threadIdx.x] = v;
    __syncthreads();
#pragma unroll
    for (int off = 1; off < 256; off <<= 1) {
        int t = (threadIdx.x >= off) ? sh[threadIdx.x - off] : 0;
        __syncthreads();
        sh[threadIdx.x] += t;
        __syncthreads();
    }
    if (i < S) base[i] = sh[threadIdx.x] - v;
    if (threadIdx.x == 255) bsum[blockIdx.x] = sh[255];
}

__global__ __launch_bounds__(512) void scanB(int* __restrict__ bsum, int NB)
{
    __shared__ int sh[512];
    int t = threadIdx.x;
    int v = (t < NB) ? bsum[t] : 0;
    sh[t] = v;
    __syncthreads();
#pragma unroll
    for (int off = 1; off < 512; off <<= 1) {
        int u = (t >= off) ? sh[t - off] : 0;
        __syncthreads();
        sh[t] += u;
        __syncthreads();
    }
    if (t < NB) bsum[t] = sh[t] - v;
}

__global__ __launch_bounds__(256) void scanC(
    int* __restrict__ base, const int* __restrict__ bsum, int S)
{
    int i = blockIdx.x * 256 + threadIdx.x;
    if (i < S) base[i] += bsum[blockIdx.x];
}

// fill: decrements cnt back to zero; writes base[S] = E sentinel.
__global__ __launch_bounds__(256) void fill_kernel(
    const int* __restrict__ src, const int* __restrict__ dst,
    const int* __restrict__ et, int* __restrict__ base,
    int* __restrict__ cnt, int* __restrict__ elist, int E, int S)
{
    int e = blockIdx.x * 256 + threadIdx.x;
    if (e == 0) base[S] = E;
    if (e >= E) return;
    int seg = dst[e] * 3 + et[e];
    int old = atomicSub(&cnt[seg], 1);
    elist[base[seg] + old - 1] = src[e];
}

// ---------------------------------------------------------------------------
// Merged prep: tiled transposes (f32->bf16 [Nout][K]) + bias concat + x->bf16.
// Grid partition: [0,1024) tr1, [1024,3072) tr2, [3072,3328) tr3,
// [3328,3338) bias, [3338,3338+convB) conv.  256 threads.
// ---------------------------------------------------------------------------
__global__ __launch_bounds__(256) void prep_all(
    const float* __restrict__ W1, const float* __restrict__ root1,
    unsigned short* __restrict__ W1t,
    const float* __restrict__ root2, const float* __restrict__ W2,
    unsigned short* __restrict__ W2cat,
    const float* __restrict__ root3, const float* __restrict__ W3,
    unsigned short* __restrict__ W3cat,
    float* __restrict__ b2cat, float* __restrict__ b3cat,
    const float* __restrict__ b2, const float* __restrict__ b3,
    const float* __restrict__ x, unsigned short* __restrict__ xb, long n8)
{
    __shared__ float sh[32][33];
    int b = blockIdx.x;
    int tc = threadIdx.x & 31, tr = threadIdx.x >> 5;
    if (b < 1024) {                                    // tr1: 1024x1024
        int bk = b & 31, bj = b >> 5;
        int k0 = bk * 32, j0 = bj * 32;
#pragma unroll
        for (int i = 0; i < 4; ++i) {
            int k = k0 + tr + i * 8;
            float v = (k < 768) ? W1[(size_t)k * 1024 + j0 + tc]
                                : root1[(size_t)(k - 768) * 1024 + j0 + tc];
            sh[tr + i * 8][tc] = v;
        }
        __syncthreads();
#pragma unroll
        for (int i = 0; i < 4; ++i)
            W1t[(size_t)(j0 + tr + i * 8) * 1024 + k0 + tc] = f2bf(sh[tc][tr + i * 8]);
    } else if (b < 3072) {                             // tr2: 2048x1024
        int bb = b - 1024;
        int bk = bb & 31, br = bb >> 5;
        int k0 = bk * 32, r0 = br * 32;
        int s = r0 >> 9, j0 = r0 & 511;
        const float* src = (s == 0) ? root2 : W2 + (size_t)(s - 1) * 524288;
#pragma unroll
        for (int i = 0; i < 4; ++i)
            sh[tr + i * 8][tc] = src[(size_t)(k0 + tr + i * 8) * 512 + j0 + tc];
        __syncthreads();
#pragma unroll
        for (int i = 0; i < 4; ++i)
            W2cat[(size_t)(r0 + tr + i * 8) * 1024 + k0 + tc] = f2bf(sh[tc][tr + i * 8]);
    } else if (b < 3328) {                             // tr3: 512x512
        int bb = b - 3072;
        int bk = bb & 15, br = bb >> 4;
        int k0 = bk * 32, r0 = br * 32;
        int s = r0 >> 7, j0 = r0 & 127;
        const float* src = (s == 0) ? root3 : W3 + (size_t)(s - 1) * 65536;
#pragma unroll
        for (int i = 0; i < 4; ++i)
            sh[tr + i * 8][tc] = src[(size_t)(k0 + tr + i * 8) * 128 + j0 + tc];
        __syncthreads();
#pragma unroll
        for (int i = 0; i < 4; ++i)
            W3cat[(size_t)(r0 + tr + i * 8) * 512 + k0 + tc] = f2bf(sh[tc][tr + i * 8]);
    } else if (b < 3338) {                             // bias concat
        int i = (b - 3328) * 256 + threadIdx.x;
        if (i < 2048) b2cat[i] = (i < 512) ? b2[i] : 0.f;
        else if (i < 2560) { int j = i - 2048; b3cat[j] = (j < 128) ? b3[j] : 0.f; }
    } else {                                           // conv x -> bf16
        long i = (long)(b - 3338) * 256 + threadIdx.x;
        if (i >= n8) return;
        const float* p = x + i * 8;
        float4 a = *(const float4*)p, bb4 = *(const float4*)(p + 4);
        ushort4 o0, o1;
        o0.x = f2bf(a.x); o0.y = f2bf(a.y); o0.z = f2bf(a.z); o0.w = f2bf(a.w);
        o1.x = f2bf(bb4.x); o1.y = f2bf(bb4.y); o1.z = f2bf(bb4.z); o1.w = f2bf(bb4.w);
        *(ushort4*)(xb + i * 8) = o0;
        *(ushort4*)(xb + i * 8 + 4) = o1;
    }
}

// Layer-1 aggregate: block = 4 waves, node n. Waves 0-2: relation w via two
// 32-lane groups (2 edges in flight, 16B/lane), fold with shfl_xor(32).
__global__ __launch_bounds__(256) void agg1_kernel(
    const unsigned short* __restrict__ xb, const int* __restrict__ base,
    const int* __restrict__ elist, unsigned short* __restrict__ Xcat)
{
    int n = blockIdx.x;
    int w = threadIdx.x >> 6, l = threadIdx.x & 63;
    if (w == 3) {
        *(ushort4*)&Xcat[(size_t)n * 1024 + 768 + l * 4] =
            *(const ushort4*)&xb[(size_t)n * 256 + l * 4];
        return;
    }
    int seg = n * 3 + w;
    int st = base[seg], len = base[seg + 1] - st;
    float norm = 1.0f / (float)(len > 0 ? len : 1);
    int g = l >> 5, c8 = (l & 31) * 8;
    float a[8];
#pragma unroll
    for (int j = 0; j < 8; ++j) a[j] = 0.f;
    for (int i = g; i < len; i += 2) {
        const unsigned short* q = xb + (size_t)elist[st + i] * 256 + c8;
        ushort4 v0 = *(const ushort4*)q;
        ushort4 v1 = *(const ushort4*)(q + 4);
        a[0] += bf2f(v0.x); a[1] += bf2f(v0.y); a[2] += bf2f(v0.z); a[3] += bf2f(v0.w);
        a[4] += bf2f(v1.x); a[5] += bf2f(v1.y); a[6] += bf2f(v1.z); a[7] += bf2f(v1.w);
    }
#pragma unroll
    for (int j = 0; j < 8; ++j) a[j] += __shfl_xor(a[j], 32);
    if (l < 32) {
        ushort4 o0, o1;
        o0.x = f2bf(a[0] * norm); o0.y = f2bf(a[1] * norm);
        o0.z = f2bf(a[2] * norm); o0.w = f2bf(a[3] * norm);
        o1.x = f2bf(a[4] * norm); o1.y = f2bf(a[5] * norm);
        o1.z = f2bf(a[6] * norm); o1.w = f2bf(a[7] * norm);
        unsigned short* d = Xcat + (size_t)n * 1024 + w * 256 + c8;
        *(ushort4*)d = o0;
        *(ushort4*)(d + 4) = o1;
    }
}

// Fused layer-2 aggregate over H2all [NP][2048] (root | r0 | r1 | r2).
// ONE NODE per block, 4 waves stride the node's edge range (chain ~3 deep),
// LDS fold; root-add + relu + bf16 pack in the fold pass.
__global__ __launch_bounds__(256) void agg2_fused(
    const unsigned short* __restrict__ H2all, unsigned short* __restrict__ h2b,
    const int* __restrict__ base, const int* __restrict__ elist)
{
    __shared__ float sh[4][512];
    int w = threadIdx.x >> 6, l = threadIdx.x & 63;
    int n = blockIdx.x;
    int c8 = l * 8;
    int s0 = base[n * 3], s1b = base[n * 3 + 1];
    int s2b = base[n * 3 + 2], s3 = base[n * 3 + 3];
    int l0 = s1b - s0, l1 = s2b - s1b, l2 = s3 - s2b;
    float nm0 = 1.f / (float)(l0 > 0 ? l0 : 1);
    float nm1 = 1.f / (float)(l1 > 0 ? l1 : 1);
    float nm2 = 1.f / (float)(l2 > 0 ? l2 : 1);
    float a[8];
#pragma unroll
    for (int j = 0; j < 8; ++j) a[j] = 0.f;
    for (int i = s0 + w; i < s3; i += 4) {
        int r = (i >= s1b) + (i >= s2b);
        float wN = (i < s1b) ? nm0 : ((i < s2b) ? nm1 : nm2);
        const unsigned short* q =
            H2all + (size_t)elist[i] * 2048 + 512 * (1 + r) + c8;
        ushort4 u0 = *(const ushort4*)q, u1 = *(const ushort4*)(q + 4);
        a[0] += bf2f(u0.x) * wN; a[1] += bf2f(u0.y) * wN;
        a[2] += bf2f(u0.z) * wN; a[3] += bf2f(u0.w) * wN;
        a[4] += bf2f(u1.x) * wN; a[5] += bf2f(u1.y) * wN;
        a[6] += bf2f(u1.z) * wN; a[7] += bf2f(u1.w) * wN;
    }
#pragma unroll
    for (int j = 0; j < 8; ++j) sh[w][c8 + j] = a[j];
    __syncthreads();
    int col = threadIdx.x * 2;
    float v0 = sh[0][col] + sh[1][col] + sh[2][col] + sh[3][col];
    float v1 = sh[0][col + 1] + sh[1][col + 1] + sh[2][col + 1] + sh[3][col + 1];
    ushort2 rt = *(const ushort2*)&H2all[(size_t)n * 2048 + col];
    v0 = fmaxf(v0 + bf2f(rt.x), 0.f);
    v1 = fmaxf(v1 + bf2f(rt.y), 0.f);
    unsigned pk = (unsigned)f2bf(v0) | ((unsigned)f2bf(v1) << 16);
    *(unsigned*)&h2b[(size_t)n * 512 + col] = pk;
}

// Fused layer-3 aggregate + FC head. Block = 4 waves = 4 nodes. FLATTENED
// edge loop over 4 lane-groups of 16 (16B/lane), fold shfl_xor(16,32).
__global__ __launch_bounds__(256) void agg3_head(
    const unsigned short* __restrict__ H3cat, const float* __restrict__ fcw,
    const float* __restrict__ fcb, const int* __restrict__ base,
    const int* __restrict__ elist, float* __restrict__ out)
{
    __shared__ float sh[4][128];
    int wid = threadIdx.x >> 6, lane = threadIdx.x & 63;
    int n = blockIdx.x * 4 + wid;
    int g = lane >> 4, c8 = (lane & 15) * 8;
    int s0 = base[n * 3], s1b = base[n * 3 + 1];
    int s2b = base[n * 3 + 2], s3 = base[n * 3 + 3];
    int l0 = s1b - s0, l1 = s2b - s1b, l2 = s3 - s2b;
    float nm0 = 1.f / (float)(l0 > 0 ? l0 : 1);
    float nm1 = 1.f / (float)(l1 > 0 ? l1 : 1);
    float nm2 = 1.f / (float)(l2 > 0 ? l2 : 1);
    float a[8];
#pragma unroll
    for (int j = 0; j < 8; ++j) a[j] = 0.f;
    for (int i = s0 + g; i < s3; i += 4) {
        int r = (i >= s1b) + (i >= s2b);
        float wN = (i < s1b) ? nm0 : ((i < s2b) ? nm1 : nm2);
        const unsigned short* q =
            H3cat + (size_t)elist[i] * 512 + 128 * (1 + r) + c8;
        ushort4 u0 = *(const ushort4*)q, u1 = *(const ushort4*)(q + 4);
        a[0] += bf2f(u0.x) * wN; a[1] += bf2f(u0.y) * wN;
        a[2] += bf2f(u0.z) * wN; a[3] += bf2f(u0.w) * wN;
        a[4] += bf2f(u1.x) * wN; a[5] += bf2f(u1.y) * wN;
        a[6] += bf2f(u1.z) * wN; a[7] += bf2f(u1.w) * wN;
    }
#pragma unroll
    for (int j = 0; j < 8; ++j) {
        a[j] += __shfl_xor(a[j], 16);
        a[j] += __shfl_xor(a[j], 32);
    }
    if (lane < 16) {
        const unsigned short* rt = H3cat + (size_t)n * 512 + c8;
        ushort4 r0 = *(const ushort4*)rt, r1 = *(const ushort4*)(rt + 4);
        sh[wid][c8 + 0] = fmaxf(a[0] + bf2f(r0.x), 0.f);
        sh[wid][c8 + 1] = fmaxf(a[1] + bf2f(r0.y), 0.f);
        sh[wid][c8 + 2] = fmaxf(a[2] + bf2f(r0.z), 0.f);
        sh[wid][c8 + 3] = fmaxf(a[3] + bf2f(r0.w), 0.f);
        sh[wid][c8 + 4] = fmaxf(a[4] + bf2f(r1.x), 0.f);
        sh[wid][c8 + 5] = fmaxf(a[5] + bf2f(r1.y), 0.f);
        sh[wid][c8 + 6] = fmaxf(a[6] + bf2f(r1.z), 0.f);
        sh[wid][c8 + 7] = fmaxf(a[7] + bf2f(r1.w), 0.f);
    }
    __syncthreads();
    float logit = 0.f;
    if (lane < 21) {
        logit = fcb[lane];
#pragma unroll
        for (int k = 0; k < 128; ++k) logit += sh[wid][k] * fcw[k * 21 + lane];
    }
    float v = (lane < 21) ? logit : -INFINITY;
#pragma unroll
    for (int off = 32; off; off >>= 1) v = fmaxf(v, __shfl_xor(v, off));
    float mx = v;
    float ex = (lane < 21) ? expf(logit - mx) : 0.f;
#pragma unroll
    for (int off = 32; off; off >>= 1) ex += __shfl_xor(ex, off);
    if (lane < 21) out[(size_t)n * 21 + lane] = logit - mx - logf(ex);
}

// Incremental layer-2 aggregate (fallback path, unchanged).
__global__ __launch_bounds__(128) void agg2_inc(
    const unsigned short* __restrict__ H2q, float* __restrict__ h2acc,
    unsigned short* __restrict__ h2b, const int* __restrict__ base,
    const int* __restrict__ elist, int r, int last)
{
    int n = blockIdx.x, t = threadIdx.x;
    int seg = n * 3 + r;
    int st = base[seg], len = base[seg + 1] - st;
    float norm = 1.0f / (float)(len > 0 ? len : 1);
    float4 s = make_float4(0.f, 0.f, 0.f, 0.f);
    for (int i = 0; i < len; ++i) {
        int sx = elist[st + i];
        ushort4 v = *(const ushort4*)&H2q[(size_t)sx * 512 + t * 4];
        s.x += bf2f(v.x); s.y += bf2f(v.y); s.z += bf2f(v.z); s.w += bf2f(v.w);
    }
    float4 a = *(const float4*)&h2acc[(size_t)n * 512 + t * 4];
    a.x += s.x * norm; a.y += s.y * norm; a.z += s.z * norm; a.w += s.w * norm;
    if (!last) {
        *(float4*)&h2acc[(size_t)n * 512 + t * 4] = a;
    } else {
        ushort4 o;
        o.x = f2bf(fmaxf(a.x, 0.f)); o.y = f2bf(fmaxf(a.y, 0.f));
        o.z = f2bf(fmaxf(a.z, 0.f)); o.w = f2bf(fmaxf(a.w, 0.f));
        *(ushort4*)&h2b[(size_t)n * 512 + t * 4] = o;
    }
}

// ---------------------------------------------------------------------------
// MFMA GEMM (round-9 proven, 84 VGPR): C = A[M,K](bf16) @ Bt[Nout,K]^T.
// 128x128 tile, BK=64, 4 waves, XOR-swizzled LDS, global_load_lds x16,
// XCD-stripe swizzled 1-D grid. DO NOT TOUCH (occupancy cliff, round 11).
// ---------------------------------------------------------------------------
__global__ __launch_bounds__(256) void gemm_mfma(
    const unsigned short* __restrict__ A, const unsigned short* __restrict__ Bt,
    const float* __restrict__ bias, void* __restrict__ C,
    int Nout, int K, int flags, int lgGX)
{
    __shared__ short __align__(16) As[8192];
    __shared__ short __align__(16) Bs[8192];
    const int tid = threadIdx.x;
    const int w = tid >> 6, l = tid & 63;

    const int nblk = (int)gridDim.x;
    const int q = nblk >> 3, rem = nblk & 7;
    const int xcd = blockIdx.x & 7, local = blockIdx.x >> 3;
    const int id2 = xcd * q + (xcd < rem ? xcd : rem) + local;
    const int row0 = (id2 >> lgGX) * 128;
    const int col0 = (id2 & ((1 << lgGX) - 1)) * 128;

    const int wm = w >> 1, wn = w & 1;
    const int lr = l >> 3, lc = l & 7;

    f32x4 acc[4][4];
#pragma unroll
    for (int i = 0; i < 4; ++i)
#pragma unroll
        for (int j = 0; j < 4; ++j) acc[i][j] = (f32x4){0.f, 0.f, 0.f, 0.f};

    for (int k0 = 0; k0 < K; k0 += 64) {
        __syncthreads();
#pragma unroll
        for (int i = 0; i < 4; ++i) {
            const int c  = i * 4 + w;
            const int r  = c * 8 + lr;
            const int c8 = lc ^ (r & 7);
            __builtin_amdgcn_global_load_lds(
                (const __attribute__((address_space(1))) void*)
                    (A + (size_t)(row0 + r) * K + k0 + c8 * 8),
                (__attribute__((address_space(3))) void*)(As + c * 512),
                16, 0, 0);
            __builtin_amdgcn_global_load_lds(
                (const __attribute__((address_space(1))) void*)
                    (Bt + (size_t)(col0 + r) * K + k0 + c8 * 8),
                (__attribute__((address_space(3))) void*)(Bs + c * 512),
                16, 0, 0);
        }
        __syncthreads();
#pragma unroll
        for (int ks = 0; ks < 2; ++ks) {
            bf16x8 af[4], bfv[4];
#pragma unroll
            for (int mf = 0; mf < 4; ++mf) {
                int r = wm * 64 + mf * 16 + (l & 15);
                int byt = (r * 128 + ks * 64 + (l >> 4) * 16) ^ ((r & 7) << 4);
                af[mf] = *(const bf16x8*)((const char*)As + byt);
            }
#pragma unroll
            for (int nf = 0; nf < 4; ++nf) {
                int r = wn * 64 + nf * 16 + (l & 15);
                int byt = (r * 128 + ks * 64 + (l >> 4) * 16) ^ ((r & 7) << 4);
                bfv[nf] = *(const bf16x8*)((const char*)Bs + byt);
            }
#pragma unroll
            for (int mf = 0; mf < 4; ++mf)
#pragma unroll
                for (int nf = 0; nf < 4; ++nf)
                    acc[mf][nf] = __builtin_amdgcn_mfma_f32_16x16x32_bf16(
                        af[mf], bfv[nf], acc[mf][nf], 0, 0, 0);
        }
    }

    const int lrow = (l >> 4) * 4;
    const int lcol = l & 15;
#pragma unroll
    for (int mf = 0; mf < 4; ++mf) {
#pragma unroll
        for (int nf = 0; nf < 4; ++nf) {
            int col = col0 + wn * 64 + nf * 16 + lcol;
            float bv = (flags & GF_BIAS) ? bias[col] : 0.f;
#pragma unroll
            for (int rr = 0; rr < 4; ++rr) {
                int row = row0 + wm * 64 + mf * 16 + lrow + rr;
                float v = acc[mf][nf][rr] + bv;
                if (flags & GF_RELU) v = fmaxf(v, 0.f);
                size_t idx = (size_t)row * Nout + col;
                if (flags & GF_BF16) ((unsigned short*)C)[idx] = f2bf(v);
                else                 ((float*)C)[idx] = v;
            }
        }
    }
}

extern "C" void kernel_launch(void* const* d_in, const int* in_sizes, int n_in,
                              void* d_out, int out_size, void* d_ws, size_t ws_size,
                              hipStream_t stream)
{
    const float* x     = (const float*)d_in[0];
    const int*   ei    = (const int*)d_in[1];
    const int*   etp   = (const int*)d_in[2];
    const float* W1    = (const float*)d_in[3];
    const float* root1 = (const float*)d_in[4];
    const float* b1    = (const float*)d_in[5];
    const float* W2    = (const float*)d_in[6];
    const float* root2 = (const float*)d_in[7];
    const float* b2    = (const float*)d_in[8];
    const float* W3    = (const float*)d_in[9];
    const float* root3 = (const float*)d_in[10];
    const float* b3    = (const float*)d_in[11];
    const float* fcw   = (const float*)d_in[12];
    const float* fcb   = (const float*)d_in[13];
    float* out = (float*)d_out;
    (void)n_in; (void)out_size;

    const int N   = in_sizes[0] / 256;           // 40000
    const int E   = in_sizes[2];                 // 500000
    const int S   = N * 3;
    const int NP  = (N + 127) / 128 * 128;       // 40064
    const int GY  = NP / 128;                    // 313
    const int NB  = (S + 255) / 256;
    const int* srcp = ei;
    const int* dstp = ei + E;

    const size_t SZ_X1024 = (size_t)NP * 1024 * 2;   // 82,051,072
    const size_t SZ_X512b = (size_t)NP * 512 * 2;    // 41,025,536
    const size_t SZ_X2048 = (size_t)NP * 2048 * 2;   // 164,102,144

    // ---- fixed region ----
    char* ws = (char*)d_ws;
    int*            cnt   = (int*)(ws + 0);                  //   480,256
    int*            base  = (int*)(ws + 480256);             //   480,256 (S+1 ints)
    int*            elist = (int*)(ws + 960512);             // 2,000,000
    float*          b2cat = (float*)(ws + 2960512);          //     8,192
    float*          b3cat = (float*)(ws + 2968704);          //     2,048
    unsigned short* W3cat = (unsigned short*)(ws + 2970752); //   524,288
    unsigned short* W2cat = (unsigned short*)(ws + 3495040); // 4,194,304
    const size_t fixed_end = 7689344;
    const size_t FUSED_NEED = 7692288 + SZ_X2048 + SZ_X1024; // 253,845,504 (proven)
    const bool fused = ws_size >= FUSED_NEED;

    char* arena;
    unsigned short *W1t, *xb, *Xcat, *h1b, *H2all, *H2q, *h2b, *H3cat;
    float* h2acc;
    if (fused) {
        arena = ws + 7692288;
        Xcat  = (unsigned short*)(arena);
        W1t   = (unsigned short*)(arena + SZ_X1024);             // dead before GEMM2
        xb    = (unsigned short*)(arena + SZ_X1024 + 2097152);   // dead before GEMM2
        h1b   = (unsigned short*)(arena + SZ_X2048);
        H2all = (unsigned short*)(arena);                        // after GEMM1
        h2b   = (unsigned short*)(arena + SZ_X2048);             // over h1b
        H3cat = (unsigned short*)(arena);                        // after agg2
        H2q = nullptr; h2acc = nullptr;
    } else {
        W1t   = (unsigned short*)(ws + fixed_end);               // 2,097,152
        arena = ws + 9789440;                                    // 4096-aligned
        Xcat  = (unsigned short*)(arena);
        h2acc = (float*)(arena);                                 // after GEMM1
        h1b   = (unsigned short*)(arena + SZ_X1024);
        h2b   = (unsigned short*)(arena + SZ_X1024);             // over h1b
        H3cat = (unsigned short*)(arena + SZ_X1024 + SZ_X512b);
        xb    = (unsigned short*)(arena + 2 * SZ_X1024);         // pre-layer1 only
        H2q   = (unsigned short*)(arena + 2 * SZ_X1024);
        H2all = nullptr;
    }
    int* bsum = (int*)(arena);          // scan scratch, dead before agg1

    // ---- CSR build: zero -> count -> scan -> fill (fill restores cnt to 0) ----
    zero_kernel<<<(30016 + 255) / 256, 256, 0, stream>>>((float*)cnt, 30016);
    count_kernel<<<(E + 255) / 256, 256, 0, stream>>>(dstp, etp, cnt, E);
    scanA<<<NB, 256, 0, stream>>>(cnt, base, bsum, S);
    scanB<<<1, 512, 0, stream>>>(bsum, NB);
    scanC<<<NB, 256, 0, stream>>>(base, bsum, S);
    fill_kernel<<<(E + 255) / 256, 256, 0, stream>>>(srcp, dstp, etp, base, cnt, elist, E, S);

    // ---- merged prep: transposes + bias concat + x->bf16 ----
    const int convB = (int)(((long)N * 32 + 255) / 256);     // 5000
    prep_all<<<3338 + convB, 256, 0, stream>>>(
        W1, root1, W1t, root2, W2, W2cat, root3, W3, W3cat,
        b2cat, b3cat, b2, b3, x, xb, (long)N * 32);

    // ---- layer 1 ----
    agg1_kernel<<<N, 256, 0, stream>>>(xb, base, elist, Xcat);
    gemm_mfma<<<8 * GY, 256, 0, stream>>>(
        Xcat, W1t, b1, h1b, 1024, 1024, GF_BIAS | GF_RELU | GF_BF16, 3);

    // ---- layer 2 ----
    if (fused) {
        gemm_mfma<<<16 * GY, 256, 0, stream>>>(
            h1b, W2cat, b2cat, H2all, 2048, 1024, GF_BIAS | GF_BF16, 4);
        agg2_fused<<<N, 256, 0, stream>>>(H2all, h2b, base, elist);
    } else {
        gemm_mfma<<<4 * GY, 256, 0, stream>>>(
            h1b, W2cat, b2, h2acc, 512, 1024, GF_BIAS, 2);
        for (int r = 0; r < 3; ++r) {
            gemm_mfma<<<4 * GY, 256, 0, stream>>>(
                h1b, W2cat + (size_t)(1 + r) * 524288, nullptr, H2q, 512, 1024, GF_BF16, 2);
            agg2_inc<<<N, 128, 0, stream>>>(H2q, h2acc, h2b, base, elist, r, r == 2);
        }
    }

    // ---- layer 3 (fused root+relations) + head ----
    gemm_mfma<<<4 * GY, 256, 0, stream>>>(
        h2b, W3cat, b3cat, H3cat, 512, 512, GF_BIAS | GF_BF16, 2);
    agg3_head<<<N / 4, 256, 0, stream>>>(H3cat, fcw, fcb, base, elist, out);
}